// Round 4
// baseline (443.731 us; speedup 1.0000x reference)
//
#include <hip/hip_runtime.h>

#define S_ 2048
#define D_ 128
#define NQ 16
#define QBLK 128
#define TBLK 32
#define KSTR 136   // lds_k row stride (shorts): [t][d] + pad
#define VSTR 40    // lds_vt row stride (shorts): [d][t] + pad
#define PSTR 40    // lds_p row stride (shorts): [row][t'] rotated

typedef short bf16x8 __attribute__((ext_vector_type(8)));
typedef float f32x4 __attribute__((ext_vector_type(4)));

static __device__ __forceinline__ unsigned cvtpk(float a, float b) {
    unsigned r;
    asm("v_cvt_pk_bf16_f32 %0, %1, %2" : "=v"(r) : "v"(a), "v"(b));
    return r;
}
static __device__ __forceinline__ float exp2a(float x) {
    float r;
    asm("v_exp_f32 %0, %1" : "=v"(r) : "v"(x));
    return r;
}
template<int CTRL> static __device__ __forceinline__ float dppf(float x) {
    return __builtin_bit_cast(float,
        __builtin_amdgcn_update_dpp(0, __builtin_bit_cast(int, x), CTRL, 0xF, 0xF, true));
}
static __device__ __forceinline__ float rsum16(float x) {
    x += dppf<0xB1>(x);   // quad_perm xor1
    x += dppf<0x4E>(x);   // quad_perm xor2
    x += dppf<0x124>(x);  // row_ror:4
    x += dppf<0x128>(x);  // row_ror:8
    return x;
}

__global__ __launch_bounds__(512, 2) void gemma2_attn_kernel(
    const float* __restrict__ q, const float* __restrict__ k,
    const float* __restrict__ v, float* __restrict__ out)
{
    // carve one shared block: K[2 grp][32t][KSTR] | Vt[2 grp][128d][VSTR] | P[8 w][32][PSTR]
    __shared__ __align__(16) short smem[2*TBLK*KSTR + 2*D_*VSTR + 8*32*PSTR];

    const int tid = threadIdx.x;
    const int w = tid >> 6, lane = tid & 63;
    const int r = lane & 15, g = lane >> 4;
    const int wg = w >> 2, wl = w & 3;     // group (tile parity), wave-in-group (row set)
    const int t256 = tid & 255;            // thread id within group

    const int flat = blockIdx.x + 8 * blockIdx.y;
    const int bh = (flat & 7) + 8 * (flat >> 6);   // XCD-friendly: same bh -> same XCD
    const int px = (flat >> 3) & 7;                // pair index

    const size_t qb = (size_t)bh * S_ * D_;
    const size_t kb = (size_t)bh * D_ * S_;

    short* lds_kg = smem + wg * (TBLK * KSTR);
    short* lds_vg = smem + 2 * TBLK * KSTR + wg * (D_ * VSTR);
    short* lds_pw = smem + 2 * TBLK * KSTR + 2 * D_ * VSTR + w * (32 * PSTR);
    float* comb = (float*)smem;            // epilogue combine buffer (K+V region)

    const float C1 = -0.333333333f, C2 = 0.133333333f;
    const float YS = 72.13475204444817f;   // 50 * log2(e)
    const float ZS = 0.08838834764831845f / 50.0f;
    const float NINF = -__builtin_inff();

    // staging maps (per group's 256 threads; group stages its own tile of 32)
    const int kt = t256 & 31, kgd = t256 >> 5;   // K: t row, d chunk of 16
    const int vd = t256 & 127, vtg = t256 >> 7;  // V: d row, t chunk of 16

    float kfl[16], vfl[16];
    auto LOAD = [&](int ssn) {
        const int t0g = ssn * 64 + wg * 32;
#pragma unroll
        for (int j = 0; j < 16; ++j)
            kfl[j] = k[kb + (size_t)(kgd * 16 + j) * S_ + t0g + kt];
#pragma unroll
        for (int i = 0; i < 16; ++i)
            vfl[i] = v[qb + (size_t)(t0g + vtg * 16 + i) * D_ + vd];
    };
    auto WRITE = [&]() {
        unsigned pk[8], pv[8];
#pragma unroll
        for (int c = 0; c < 8; ++c) pk[c] = cvtpk(kfl[2 * c], kfl[2 * c + 1]);
#pragma unroll
        for (int c = 0; c < 8; ++c) pv[c] = cvtpk(vfl[2 * c], vfl[2 * c + 1]);
        uint4 a0 = {pk[0], pk[1], pk[2], pk[3]}, a1 = {pk[4], pk[5], pk[6], pk[7]};
        *(uint4*)&lds_kg[kt * KSTR + kgd * 16] = a0;
        *(uint4*)&lds_kg[kt * KSTR + kgd * 16 + 8] = a1;
        uint4 b0 = {pv[0], pv[1], pv[2], pv[3]}, b1 = {pv[4], pv[5], pv[6], pv[7]};
        *(uint4*)&lds_vg[vd * VSTR + vtg * 16] = b0;
        *(uint4*)&lds_vg[vd * VSTR + vtg * 16 + 8] = b1;
    };

    LOAD(0);

#pragma unroll 1
    for (int ph = 0; ph < 2; ++ph) {
        const int qi = ph ? (NQ - 1 - px) : px;
        const int q0 = qi * QBLK;
        const int nss = 2 * qi + 2;        // supersteps (2 tiles each)

        // Q fragments: rows q0 + wl*32 + rf*16 + r
        bf16x8 qf[2][4];
#pragma unroll
        for (int rf = 0; rf < 2; ++rf)
#pragma unroll
            for (int kk = 0; kk < 4; ++kk) {
                const float* qp = q + qb + (size_t)(q0 + wl * 32 + rf * 16 + r) * D_ + kk * 32 + g * 8;
                uint4 t4 = {cvtpk(qp[0], qp[1]), cvtpk(qp[2], qp[3]),
                            cvtpk(qp[4], qp[5]), cvtpk(qp[6], qp[7])};
                qf[rf][kk] = __builtin_bit_cast(bf16x8, t4);
            }

        f32x4 oacc[2][8];
#pragma unroll
        for (int rf = 0; rf < 2; ++rf)
#pragma unroll
            for (int db = 0; db < 8; ++db) oacc[rf][db] = (f32x4){0.f, 0.f, 0.f, 0.f};
        float l_p[2][4];
#pragma unroll
        for (int rf = 0; rf < 2; ++rf)
#pragma unroll
            for (int j = 0; j < 4; ++j) l_p[rf][j] = 0.f;

        const int wrlo = q0 + wl * 32;     // wave's first row

#pragma unroll 1
        for (int ss = 0; ss < nss; ++ss) {
            const int t0 = ss * 64 + wg * 32;   // this group's tile
            __syncthreads();                    // prev compute done reading LDS
            WRITE();
            __syncthreads();                    // tile visible to group
            if (ss + 1 < nss) LOAD(ss + 1);     // overlaps compute below
            else if (ph == 0) LOAD(0);          // prefetch next phase's first tiles

            if (t0 > wrlo + 31) continue;       // wave fully masked

            // ---- QK^T: sf[rf][nb], rows g*4+reg (+rf*16), col t0 + nb*16 + r
            f32x4 sf[2][2];
#pragma unroll
            for (int rf = 0; rf < 2; ++rf)
#pragma unroll
                for (int nb = 0; nb < 2; ++nb) sf[rf][nb] = (f32x4){0.f, 0.f, 0.f, 0.f};
#pragma unroll
            for (int nb = 0; nb < 2; ++nb) {
                const int trow = nb * 16 + r;
#pragma unroll
                for (int kk = 0; kk < 4; ++kk) {
                    bf16x8 bf = *(const bf16x8*)&lds_kg[trow * KSTR + kk * 32 + g * 8];
                    sf[0][nb] = __builtin_amdgcn_mfma_f32_16x16x32_bf16(qf[0][kk], bf, sf[0][nb], 0, 0, 0);
                    sf[1][nb] = __builtin_amdgcn_mfma_f32_16x16x32_bf16(qf[1][kk], bf, sf[1][nb], 0, 0, 0);
                }
            }

            // ---- fixed-max softmax: p = exp2((y-50)*log2e); no reductions in loop
            const bool need_mask = (t0 + 31 > wrlo);   // wave-uniform
            const int pcol0 = (r + 8 * g) & 31;        // rotated P col for nb=0 (rot=g)
#pragma unroll
            for (int rf = 0; rf < 2; ++rf)
#pragma unroll
                for (int reg = 0; reg < 4; ++reg) {
                    const int irow = q0 + wl * 32 + rf * 16 + g * 4 + reg;
                    float p0, p1;
                    {
                        float z = sf[rf][0][reg] * ZS;
                        float z2 = z * z;
                        float t = z * __builtin_fmaf(z2, __builtin_fmaf(z2, C2, C1), 1.0f);
                        float yl = __builtin_fmaf(t, YS, -YS);
                        if (need_mask && (t0 + r > irow)) yl = NINF;
                        p0 = exp2a(yl);
                    }
                    {
                        float z = sf[rf][1][reg] * ZS;
                        float z2 = z * z;
                        float t = z * __builtin_fmaf(z2, __builtin_fmaf(z2, C2, C1), 1.0f);
                        float yl = __builtin_fmaf(t, YS, -YS);
                        if (need_mask && (t0 + 16 + r > irow)) yl = NINF;
                        p1 = exp2a(yl);
                    }
                    l_p[rf][reg] += p0 + p1;
                    const unsigned pkd = cvtpk(p0, p1);
                    const int prow = rf * 16 + g * 4 + reg;
                    lds_pw[prow * PSTR + pcol0] = (short)(pkd & 0xffff);
                    lds_pw[prow * PSTR + (pcol0 ^ 16)] = (short)(pkd >> 16);
                }

            // ---- PV (K-dim = 32 -> one MFMA per (rf,db))
            asm volatile("s_waitcnt lgkmcnt(0)" ::: "memory");
            __builtin_amdgcn_sched_barrier(0);
            bf16x8 pa[2];
#pragma unroll
            for (int rf = 0; rf < 2; ++rf)
                pa[rf] = *(const bf16x8*)&lds_pw[(rf * 16 + r) * PSTR + 8 * ((g + (r >> 2)) & 3)];
#pragma unroll
            for (int db = 0; db < 8; ++db) {
                bf16x8 vb = *(const bf16x8*)&lds_vg[(db * 16 + r) * VSTR + g * 8];
                oacc[0][db] = __builtin_amdgcn_mfma_f32_16x16x32_bf16(pa[0], vb, oacc[0][db], 0, 0, 0);
                oacc[1][db] = __builtin_amdgcn_mfma_f32_16x16x32_bf16(pa[1], vb, oacc[1][db], 0, 0, 0);
            }
        } // ss

        // ---- combine groups (fixed max -> plain addition), 4 rounds through LDS
#pragma unroll 1
        for (int rd = 0; rd < 4; ++rd) {
            const int rf = rd >> 1, dh = (rd & 1) * 4, lh = (rd & 1) * 2;
            __syncthreads();
            if (wg == 1) {
                float* c = comb + t256 * 20;
#pragma unroll
                for (int db = 0; db < 4; ++db)
                    *(f32x4*)(c + db * 4) = oacc[rf][dh + db];
                c[16] = l_p[rf][lh];
                c[17] = l_p[rf][lh + 1];
            }
            __syncthreads();
            if (wg == 0) {
                const float* c = comb + t256 * 20;
#pragma unroll
                for (int db = 0; db < 4; ++db) {
                    f32x4 t = *(const f32x4*)(c + db * 4);
                    oacc[rf][dh + db] += t;
                }
                l_p[rf][lh] += c[16];
                l_p[rf][lh + 1] += c[17];
            }
        }

        if (wg == 0) {
#pragma unroll
            for (int rf = 0; rf < 2; ++rf) {
                float invl[4];
#pragma unroll
                for (int reg = 0; reg < 4; ++reg)
                    invl[reg] = 1.0f / rsum16(l_p[rf][reg]);
#pragma unroll
                for (int db = 0; db < 8; ++db)
#pragma unroll
                    for (int reg = 0; reg < 4; ++reg) {
                        const int row = q0 + wl * 32 + rf * 16 + g * 4 + reg;
                        out[qb + (size_t)row * D_ + db * 16 + r] = oacc[rf][db][reg] * invl[reg];
                    }
            }
        }
    } // ph
}

extern "C" void kernel_launch(void* const* d_in, const int* in_sizes, int n_in,
                              void* d_out, int out_size, void* d_ws, size_t ws_size,
                              hipStream_t stream) {
    const float* q = (const float*)d_in[0];
    const float* k = (const float*)d_in[1];
    const float* v = (const float*)d_in[2];
    float* out = (float*)d_out;
    dim3 grid(8, 32);
    gemma2_attn_kernel<<<grid, dim3(512), 0, stream>>>(q, k, v, out);
}

// Round 5
// 99.375 us; speedup vs baseline: 4.4652x; 4.4652x over previous
//
#include <hip/hip_runtime.h>

#define S_ 2048
#define D_ 128
#define NQ 16
#define QBLK 128
#define TBLK 32
#define KSTR 136   // lds_k row stride (shorts): [t][d] + pad
#define VSTR 40    // lds_vt row stride (shorts): [d][t] + pad
#define PSTR 40    // lds_p row stride (shorts): [row][t'] rotated

typedef short bf16x8 __attribute__((ext_vector_type(8)));
typedef float f32x4 __attribute__((ext_vector_type(4)));

static __device__ __forceinline__ unsigned cvtpk(float a, float b) {
    unsigned r;
    asm("v_cvt_pk_bf16_f32 %0, %1, %2" : "=v"(r) : "v"(a), "v"(b));
    return r;
}
static __device__ __forceinline__ float exp2a(float x) {
    float r;
    asm("v_exp_f32 %0, %1" : "=v"(r) : "v"(x));
    return r;
}
template<int CTRL> static __device__ __forceinline__ float dppf(float x) {
    return __builtin_bit_cast(float,
        __builtin_amdgcn_update_dpp(0, __builtin_bit_cast(int, x), CTRL, 0xF, 0xF, true));
}
static __device__ __forceinline__ float rsum16(float x) {
    x += dppf<0xB1>(x);   // quad_perm xor1
    x += dppf<0x4E>(x);   // quad_perm xor2
    x += dppf<0x124>(x);  // row_ror:4
    x += dppf<0x128>(x);  // row_ror:8
    return x;
}

__global__ __launch_bounds__(512, 2) void gemma2_attn_kernel(
    const float* __restrict__ q, const float* __restrict__ k,
    const float* __restrict__ v, float* __restrict__ out)
{
    // K[2 grp][32t][KSTR] | Vt[2 grp][128d][VSTR] | P[8 w][32][PSTR]
    __shared__ __align__(16) short smem[2*TBLK*KSTR + 2*D_*VSTR + 8*32*PSTR];

    const int tid = threadIdx.x;
    const int w = tid >> 6, lane = tid & 63;
    const int r = lane & 15, g = lane >> 4;
    const int wg = w >> 2, wl = w & 3;     // group (tile parity), wave-in-group (row set)
    const int t256 = tid & 255;

    const int flat = blockIdx.x + 8 * blockIdx.y;
    const int bh = (flat & 7) + 8 * (flat >> 6);   // XCD-friendly
    const int px = (flat >> 3) & 7;                // pair index

    const size_t qb = (size_t)bh * S_ * D_;
    const size_t kb = (size_t)bh * D_ * S_;

    short* lds_kg = smem + wg * (TBLK * KSTR);
    short* lds_vg = smem + 2 * TBLK * KSTR + wg * (D_ * VSTR);
    short* lds_pw = smem + 2 * TBLK * KSTR + 2 * D_ * VSTR + w * (32 * PSTR);
    float* comb = (float*)smem;            // epilogue combine buffer (aliases K+V region)

    const float C1 = -0.333333333f, C2 = 0.133333333f;
    const float YS = 72.13475204444817f;   // 50 * log2(e)
    const float ZS = 0.08838834764831845f / 50.0f;
    const float NINF = -__builtin_inff();

    const int kt = t256 & 31, kgd = t256 >> 5;   // K staging: t row, d chunk of 16
    const int vd = t256 & 127, vtg = t256 >> 7;  // V staging: d row, t chunk of 16

    float kfl[16], vfl[16];
    auto LOAD = [&](int ssn) {
        const int t0g = ssn * 64 + wg * 32;
#pragma unroll
        for (int j = 0; j < 16; ++j)
            kfl[j] = k[kb + (size_t)(kgd * 16 + j) * S_ + t0g + kt];
#pragma unroll
        for (int i = 0; i < 16; ++i)
            vfl[i] = v[qb + (size_t)(t0g + vtg * 16 + i) * D_ + vd];
    };
    auto WRITE = [&]() {
        unsigned pk[8], pv[8];
#pragma unroll
        for (int c = 0; c < 8; ++c) pk[c] = cvtpk(kfl[2 * c], kfl[2 * c + 1]);
#pragma unroll
        for (int c = 0; c < 8; ++c) pv[c] = cvtpk(vfl[2 * c], vfl[2 * c + 1]);
        uint4 a0 = {pk[0], pk[1], pk[2], pk[3]}, a1 = {pk[4], pk[5], pk[6], pk[7]};
        *(uint4*)&lds_kg[kt * KSTR + kgd * 16] = a0;
        *(uint4*)&lds_kg[kt * KSTR + kgd * 16 + 8] = a1;
        uint4 b0 = {pv[0], pv[1], pv[2], pv[3]}, b1 = {pv[4], pv[5], pv[6], pv[7]};
        *(uint4*)&lds_vg[vd * VSTR + vtg * 16] = b0;
        *(uint4*)&lds_vg[vd * VSTR + vtg * 16 + 8] = b1;
    };

    LOAD(0);

#pragma unroll 1
    for (int ph = 0; ph < 2; ++ph) {
        const int qi = ph ? (NQ - 1 - px) : px;
        const int q0 = qi * QBLK;
        const int nss = 2 * qi + 2;

        // Q fragments: rows q0 + wl*32 + rf*16 + r
        bf16x8 qf[2][4];
#pragma unroll
        for (int rf = 0; rf < 2; ++rf)
#pragma unroll
            for (int kk = 0; kk < 4; ++kk) {
                const float* qp = q + qb + (size_t)(q0 + wl * 32 + rf * 16 + r) * D_ + kk * 32 + g * 8;
                uint4 t4 = {cvtpk(qp[0], qp[1]), cvtpk(qp[2], qp[3]),
                            cvtpk(qp[4], qp[5]), cvtpk(qp[6], qp[7])};
                qf[rf][kk] = __builtin_bit_cast(bf16x8, t4);
            }

        f32x4 oacc[2][8];
#pragma unroll
        for (int rf = 0; rf < 2; ++rf)
#pragma unroll
            for (int db = 0; db < 8; ++db) oacc[rf][db] = (f32x4){0.f, 0.f, 0.f, 0.f};
        float l_p[2][4];
#pragma unroll
        for (int rf = 0; rf < 2; ++rf)
#pragma unroll
            for (int j = 0; j < 4; ++j) l_p[rf][j] = 0.f;

        const int wrlo = q0 + wl * 32;

#pragma unroll 1
        for (int ss = 0; ss < nss; ++ss) {
            const int t0 = ss * 64 + wg * 32;
            __syncthreads();                    // prev compute done reading LDS
            WRITE();
            __syncthreads();                    // tile visible
            if (ss + 1 < nss) LOAD(ss + 1);     // overlaps compute below
            else if (ph == 0) LOAD(0);

            if (t0 > wrlo + 31) continue;

            // ---- QK^T
            f32x4 sf[2][2];
#pragma unroll
            for (int rf = 0; rf < 2; ++rf)
#pragma unroll
                for (int nb = 0; nb < 2; ++nb) sf[rf][nb] = (f32x4){0.f, 0.f, 0.f, 0.f};
#pragma unroll
            for (int nb = 0; nb < 2; ++nb) {
                const int trow = nb * 16 + r;
#pragma unroll
                for (int kk = 0; kk < 4; ++kk) {
                    bf16x8 bf = *(const bf16x8*)&lds_kg[trow * KSTR + kk * 32 + g * 8];
                    sf[0][nb] = __builtin_amdgcn_mfma_f32_16x16x32_bf16(qf[0][kk], bf, sf[0][nb], 0, 0, 0);
                    sf[1][nb] = __builtin_amdgcn_mfma_f32_16x16x32_bf16(qf[1][kk], bf, sf[1][nb], 0, 0, 0);
                }
            }

            // ---- fixed-max softmax: p = exp2((y-50)*log2e); no per-tile reductions
            const bool need_mask = (t0 + 31 > wrlo);
            const int pcol0 = (r + 8 * g) & 31;
#pragma unroll
            for (int rf = 0; rf < 2; ++rf)
#pragma unroll
                for (int reg = 0; reg < 4; ++reg) {
                    const int irow = q0 + wl * 32 + rf * 16 + g * 4 + reg;
                    float p0, p1;
                    {
                        float z = sf[rf][0][reg] * ZS;
                        float z2 = z * z;
                        float t = z * __builtin_fmaf(z2, __builtin_fmaf(z2, C2, C1), 1.0f);
                        float yl = __builtin_fmaf(t, YS, -YS);
                        if (need_mask && (t0 + r > irow)) yl = NINF;
                        p0 = exp2a(yl);
                    }
                    {
                        float z = sf[rf][1][reg] * ZS;
                        float z2 = z * z;
                        float t = z * __builtin_fmaf(z2, __builtin_fmaf(z2, C2, C1), 1.0f);
                        float yl = __builtin_fmaf(t, YS, -YS);
                        if (need_mask && (t0 + 16 + r > irow)) yl = NINF;
                        p1 = exp2a(yl);
                    }
                    l_p[rf][reg] += p0 + p1;
                    const unsigned pkd = cvtpk(p0, p1);
                    const int prow = rf * 16 + g * 4 + reg;
                    lds_pw[prow * PSTR + pcol0] = (short)(pkd & 0xffff);
                    lds_pw[prow * PSTR + (pcol0 ^ 16)] = (short)(pkd >> 16);
                }

            // ---- PV
            asm volatile("s_waitcnt lgkmcnt(0)" ::: "memory");
            __builtin_amdgcn_sched_barrier(0);
            bf16x8 pa[2];
#pragma unroll
            for (int rf = 0; rf < 2; ++rf)
                pa[rf] = *(const bf16x8*)&lds_pw[(rf * 16 + r) * PSTR + 8 * ((g + (r >> 2)) & 3)];
#pragma unroll
            for (int db = 0; db < 8; ++db) {
                bf16x8 vb = *(const bf16x8*)&lds_vg[(db * 16 + r) * VSTR + g * 8];
                oacc[0][db] = __builtin_amdgcn_mfma_f32_16x16x32_bf16(pa[0], vb, oacc[0][db], 0, 0, 0);
                oacc[1][db] = __builtin_amdgcn_mfma_f32_16x16x32_bf16(pa[1], vb, oacc[1][db], 0, 0, 0);
            }
        } // ss

        // ---- combine groups: STATIC indices only (rule #20 — no runtime acc indexing)
#define COMB_ROUND(RF, HALF)                                           \
        do {                                                           \
            __syncthreads();                                           \
            if (wg == 1) {                                             \
                float* c = comb + t256 * 21;                           \
                *(f32x4*)(c + 0)  = oacc[RF][(HALF)*4 + 0];            \
                *(f32x4*)(c + 4)  = oacc[RF][(HALF)*4 + 1];            \
                *(f32x4*)(c + 8)  = oacc[RF][(HALF)*4 + 2];            \
                *(f32x4*)(c + 12) = oacc[RF][(HALF)*4 + 3];            \
                c[16] = l_p[RF][(HALF)*2];                             \
                c[17] = l_p[RF][(HALF)*2 + 1];                         \
            }                                                          \
            __syncthreads();                                           \
            if (wg == 0) {                                             \
                const float* c = comb + t256 * 21;                     \
                oacc[RF][(HALF)*4 + 0] += *(const f32x4*)(c + 0);      \
                oacc[RF][(HALF)*4 + 1] += *(const f32x4*)(c + 4);      \
                oacc[RF][(HALF)*4 + 2] += *(const f32x4*)(c + 8);      \
                oacc[RF][(HALF)*4 + 3] += *(const f32x4*)(c + 12);     \
                l_p[RF][(HALF)*2]     += c[16];                        \
                l_p[RF][(HALF)*2 + 1] += c[17];                        \
            }                                                          \
        } while (0)

        COMB_ROUND(0, 0);
        COMB_ROUND(0, 1);
        COMB_ROUND(1, 0);
        COMB_ROUND(1, 1);
#undef COMB_ROUND

        if (wg == 0) {
#pragma unroll
            for (int rf = 0; rf < 2; ++rf) {
                float invl[4];
#pragma unroll
                for (int reg = 0; reg < 4; ++reg)
                    invl[reg] = 1.0f / rsum16(l_p[rf][reg]);
#pragma unroll
                for (int db = 0; db < 8; ++db)
#pragma unroll
                    for (int reg = 0; reg < 4; ++reg) {
                        const int row = q0 + wl * 32 + rf * 16 + g * 4 + reg;
                        out[qb + (size_t)row * D_ + db * 16 + r] = oacc[rf][db][reg] * invl[reg];
                    }
            }
        }
    } // ph
}

extern "C" void kernel_launch(void* const* d_in, const int* in_sizes, int n_in,
                              void* d_out, int out_size, void* d_ws, size_t ws_size,
                              hipStream_t stream) {
    const float* q = (const float*)d_in[0];
    const float* k = (const float*)d_in[1];
    const float* v = (const float*)d_in[2];
    float* out = (float*)d_out;
    dim3 grid(8, 32);
    gemma2_attn_kernel<<<grid, dim3(512), 0, stream>>>(q, k, v, out);
}